// Round 2
// baseline (659.171 us; speedup 1.0000x reference)
//
#include <hip/hip_runtime.h>
#include <hip/hip_bf16.h>
#include <math.h>

#define DEVI __device__ __forceinline__

typedef __bf16 bf16x8 __attribute__((ext_vector_type(8)));
typedef float f32x4 __attribute__((ext_vector_type(4)));
typedef unsigned int u32x4 __attribute__((ext_vector_type(4)));
typedef unsigned short u16;

DEVI u16 f2bf(float f) {
    __hip_bfloat16 h = __float2bfloat16(f);
    return __builtin_bit_cast(u16, h);
}
DEVI float bf2f(u16 u) {
    unsigned int x = ((unsigned int)u) << 16;
    return __builtin_bit_cast(float, x);
}
DEVI float gelu_f(float x) { return 0.5f * x * (1.f + erff(x * 0.70710678118654752f)); }
DEVI float sigm(float x) { return 1.f / (1.f + expf(-x)); }

DEVI bf16x8 ldfrag(const u16* p) {
    return __builtin_bit_cast(bf16x8, *reinterpret_cast<const u32x4*>(p));
}

// ---------------- zero fill ----------------
__global__ __launch_bounds__(256) void zero_k(float* __restrict__ p) {
    p[(long long)blockIdx.x * 256 + threadIdx.x] = 0.f;
}

// ---------------- transpose + cast fp32 -> bf16, out[c][r] = in[r][c] ----------------
__global__ __launch_bounds__(256) void tcast_k(const float* __restrict__ in, u16* __restrict__ out,
                                               int R, int C) {
    __shared__ float tile[32][33];
    int c0 = blockIdx.x * 32, r0 = blockIdx.y * 32;
    for (int ry = threadIdx.y; ry < 32; ry += 8)
        tile[ry][threadIdx.x] = in[(long long)(r0 + ry) * C + c0 + threadIdx.x];
    __syncthreads();
    for (int cy = threadIdx.y; cy < 32; cy += 8)
        out[(long long)(c0 + cy) * R + r0 + threadIdx.x] = f2bf(tile[threadIdx.x][cy]);
}

// ---------------- layernorm over 768, optional residual-add input + x1 store ----------------
__global__ __launch_bounds__(256) void ln_k(const float* __restrict__ in1, const float* __restrict__ in2,
                                            const float* __restrict__ w, const float* __restrict__ b,
                                            u16* __restrict__ outbf, float* __restrict__ x1out) {
    int row = blockIdx.x;
    long long ro = (long long)row * 768;
    __shared__ float lds1[4], lds2[4];
    float v[3];
    float s = 0.f, sq = 0.f;
#pragma unroll
    for (int j = 0; j < 3; j++) {
        int c = threadIdx.x + j * 256;
        float x = in1[ro + c];
        if (in2) x += in2[ro + c];
        v[j] = x; s += x; sq += x * x;
    }
    if (x1out) {
#pragma unroll
        for (int j = 0; j < 3; j++) x1out[ro + threadIdx.x + j * 256] = v[j];
    }
    for (int off = 32; off; off >>= 1) { s += __shfl_down(s, off); sq += __shfl_down(sq, off); }
    int wid = threadIdx.x >> 6;
    if ((threadIdx.x & 63) == 0) { lds1[wid] = s; lds2[wid] = sq; }
    __syncthreads();
    s = lds1[0] + lds1[1] + lds1[2] + lds1[3];
    sq = lds2[0] + lds2[1] + lds2[2] + lds2[3];
    float mu = s * (1.f / 768.f);
    float var = sq * (1.f / 768.f) - mu * mu;
    float rs = rsqrtf(var + 1e-5f);
#pragma unroll
    for (int j = 0; j < 3; j++) {
        int c = threadIdx.x + j * 256;
        outbf[ro + c] = f2bf((v[j] - mu) * rs * w[c] + b[c]);
    }
}

// ---------------- generic MFMA GEMM: C = A @ B_t^T ; A[M][K] bf16, B_t[N][K] bf16 ----------------
struct GemmP {
    const u16* A; const u16* B;
    float* outF; u16* outB;
    const float* bias; const float* res;
    int M, N, K, lda, ldb, ldc;
    int epi;  // 0:f32+bias 1:bf16+bias 2:bf16+bias+gelu 3:f32+bias+res
};

__global__ __launch_bounds__(256) void gemm_bt(GemmP p) {
    constexpr int BM = 128, BN = 128;
    __shared__ u16 As[BM * 32];
    __shared__ u16 Bs[BN * 32];
    const int tid = threadIdx.x, lane = tid & 63, wid = tid >> 6;
    const int l16 = lane & 15, qd = lane >> 4;
    const int bm0 = blockIdx.y * BM, bn0 = blockIdx.x * BN;
    const int wm0 = (wid >> 1) * 64, wn0 = (wid & 1) * 64;
    f32x4 acc[4][4] = {};
    for (int k0 = 0; k0 < p.K; k0 += 32) {
        for (int c = tid; c < BM * 4; c += 256) {
            int row = c >> 2, kc = (c & 3) * 8;
            *reinterpret_cast<u32x4*>(&As[row * 32 + kc]) =
                *reinterpret_cast<const u32x4*>(&p.A[(long long)(bm0 + row) * p.lda + k0 + kc]);
            *reinterpret_cast<u32x4*>(&Bs[row * 32 + kc]) =
                *reinterpret_cast<const u32x4*>(&p.B[(long long)(bn0 + row) * p.ldb + k0 + kc]);
        }
        __syncthreads();
        bf16x8 af[4], bv[4];
#pragma unroll
        for (int i = 0; i < 4; i++) af[i] = ldfrag(&As[(wm0 + i * 16 + l16) * 32 + qd * 8]);
#pragma unroll
        for (int j = 0; j < 4; j++) bv[j] = ldfrag(&Bs[(wn0 + j * 16 + l16) * 32 + qd * 8]);
#pragma unroll
        for (int i = 0; i < 4; i++)
#pragma unroll
            for (int j = 0; j < 4; j++)
                acc[i][j] = __builtin_amdgcn_mfma_f32_16x16x32_bf16(af[i], bv[j], acc[i][j], 0, 0, 0);
        __syncthreads();
    }
#pragma unroll
    for (int i = 0; i < 4; i++)
#pragma unroll
        for (int j = 0; j < 4; j++)
#pragma unroll
            for (int r = 0; r < 4; r++) {
                int row = bm0 + wm0 + i * 16 + qd * 4 + r;
                int col = bn0 + wn0 + j * 16 + l16;
                float v = acc[i][j][r];
                long long o = (long long)row * p.ldc + col;
                switch (p.epi) {
                    case 0: p.outF[o] = v + p.bias[col]; break;
                    case 1: p.outB[o] = f2bf(v + p.bias[col]); break;
                    case 2: p.outB[o] = f2bf(gelu_f(v + p.bias[col])); break;
                    default: p.outF[o] = v + p.bias[col] + p.res[o]; break;
                }
            }
}

// ---------------- repack qkv (bf16 [4096][2304]) into per-head q,k,v [48][1024][64] ----------------
__global__ __launch_bounds__(256) void repack_qkv_k(const u16* __restrict__ qkvB,
                                                    u16* __restrict__ qh, u16* __restrict__ kh,
                                                    u16* __restrict__ vh) {
    long long idx = (long long)blockIdx.x * 256 + threadIdx.x;  // < 4096*768
    int r = (int)(idx / 768), c = (int)(idx % 768);
    int b = r >> 10, n = r & 1023, h = c >> 6, d = c & 63;
    long long src = (long long)r * 2304;
    long long o = ((long long)(b * 12 + h) * 1024 + n) * 64 + d;
    qh[o] = f2bf(bf2f(qkvB[src + c]) * 0.125f);
    kh[o] = qkvB[src + 768 + c];
    vh[o] = qkvB[src + 1536 + c];
}

// ---------------- gwn = softmax(gelu(v @ gp^T)) per head, padded to 64 cols, bf16 ----------------
__global__ __launch_bounds__(256) void gw0_k(const u16* __restrict__ vh, const float* __restrict__ gp_w,
                                             u16* __restrict__ gwn) {
    int z = blockIdx.y, n0 = blockIdx.x * 64;
    int h = z % 12;
    __shared__ float gps[49 * 64];
    __shared__ float vs[64 * 64];
    __shared__ float gws[64 * 52];
    for (int i = threadIdx.x; i < 49 * 64; i += 256) gps[i] = gp_w[h * 3136 + i];
    for (int i = threadIdx.x; i < 64 * 64; i += 256) {
        int n = i >> 6, d = i & 63;
        vs[i] = bf2f(vh[((long long)z * 1024 + n0 + n) * 64 + d]);
    }
    __syncthreads();
    for (int o = threadIdx.x; o < 64 * 49; o += 256) {
        int n = o / 49, m = o % 49;
        float s = 0.f;
#pragma unroll 8
        for (int kk = 0; kk < 64; kk++) s += vs[n * 64 + kk] * gps[m * 64 + kk];
        gws[n * 52 + m] = gelu_f(s);
    }
    __syncthreads();
    if (threadIdx.x < 64) {
        int n = threadIdx.x;
        float mx = -1e30f;
        for (int m = 0; m < 49; m++) mx = fmaxf(mx, gws[n * 52 + m]);
        float se = 0.f;
        for (int m = 0; m < 49; m++) se += expf(gws[n * 52 + m] - mx);
        float inv = 1.f / se;
        long long o = ((long long)z * 1024 + n0 + n) * 64;
        for (int m = 0; m < 49; m++) gwn[o + m] = f2bf(expf(gws[n * 52 + m] - mx) * inv);
        for (int m = 49; m < 64; m++) gwn[o + m] = 0;
    }
}

// ---------------- fused dual GEMM: t = (q@k^T) * (gwn@gwn^T), bf16 ----------------
__global__ __launch_bounds__(256) void attn_tg_k(const u16* __restrict__ qh, const u16* __restrict__ kh,
                                                 const u16* __restrict__ gwn, u16* __restrict__ t) {
    __shared__ u16 As[128 * 32];
    __shared__ u16 Bs[128 * 32];
    const int tid = threadIdx.x, lane = tid & 63, wid = tid >> 6;
    const int l16 = lane & 15, qd = lane >> 4;
    const int bm0 = blockIdx.y * 128, bn0 = blockIdx.x * 128, z = blockIdx.z;
    const int wm0 = (wid >> 1) * 64, wn0 = (wid & 1) * 64;
    const u16* qz = qh + (long long)z * 65536;
    const u16* kz = kh + (long long)z * 65536;
    const u16* gz = gwn + (long long)z * 65536;
    f32x4 accS[4][4] = {};
    f32x4 accG[4][4] = {};
    for (int ph = 0; ph < 2; ph++) {
        const u16* pa = ph ? gz : qz;
        const u16* pb = ph ? gz : kz;
        for (int k0 = 0; k0 < 64; k0 += 32) {
            __syncthreads();
            for (int c = tid; c < 512; c += 256) {
                int row = c >> 2, kc = (c & 3) * 8;
                *reinterpret_cast<u32x4*>(&As[row * 32 + kc]) =
                    *reinterpret_cast<const u32x4*>(&pa[(long long)(bm0 + row) * 64 + k0 + kc]);
                *reinterpret_cast<u32x4*>(&Bs[row * 32 + kc]) =
                    *reinterpret_cast<const u32x4*>(&pb[(long long)(bn0 + row) * 64 + k0 + kc]);
            }
            __syncthreads();
            bf16x8 af[4], bv[4];
#pragma unroll
            for (int i = 0; i < 4; i++) af[i] = ldfrag(&As[(wm0 + i * 16 + l16) * 32 + qd * 8]);
#pragma unroll
            for (int j = 0; j < 4; j++) bv[j] = ldfrag(&Bs[(wn0 + j * 16 + l16) * 32 + qd * 8]);
            if (ph == 0) {
#pragma unroll
                for (int i = 0; i < 4; i++)
#pragma unroll
                    for (int j = 0; j < 4; j++)
                        accS[i][j] = __builtin_amdgcn_mfma_f32_16x16x32_bf16(af[i], bv[j], accS[i][j], 0, 0, 0);
            } else {
#pragma unroll
                for (int i = 0; i < 4; i++)
#pragma unroll
                    for (int j = 0; j < 4; j++)
                        accG[i][j] = __builtin_amdgcn_mfma_f32_16x16x32_bf16(af[i], bv[j], accG[i][j], 0, 0, 0);
            }
        }
    }
    long long zoff = (long long)z * 1048576;
#pragma unroll
    for (int i = 0; i < 4; i++)
#pragma unroll
        for (int j = 0; j < 4; j++)
#pragma unroll
            for (int r = 0; r < 4; r++) {
                int row = bm0 + wm0 + i * 16 + qd * 4 + r;
                int col = bn0 + wn0 + j * 16 + l16;
                t[zoff + (long long)row * 1024 + col] = f2bf(accS[i][j][r] * accG[i][j][r]);
            }
}

// ---------------- per-row softmax of t, in place (P = exp(t)/rowsum) ----------------
__global__ __launch_bounds__(256) void rowsoft_k(u16* __restrict__ t) {
    int n = blockIdx.x, z = blockIdx.y;
    __shared__ float lds[4];
    long long roff = (long long)z * 1048576 + (long long)n * 1024;
    float e[4];
    float s = 0.f;
#pragma unroll
    for (int j = 0; j < 4; j++) {
        e[j] = expf(bf2f(t[roff + threadIdx.x + j * 256]));  // |t| <~ 2 -> no max-sub needed
        s += e[j];
    }
    for (int off = 32; off; off >>= 1) s += __shfl_down(s, off);
    if ((threadIdx.x & 63) == 0) lds[threadIdx.x >> 6] = s;
    __syncthreads();
    float inv = 1.f / (lds[0] + lds[1] + lds[2] + lds[3]);
#pragma unroll
    for (int j = 0; j < 4; j++) t[roff + threadIdx.x + j * 256] = f2bf(e[j] * inv);
}

// ---------------- column sums of P over n ----------------
__global__ __launch_bounds__(256) void colsumP_k(const u16* __restrict__ P, float* __restrict__ colsumP) {
    int m = blockIdx.x * 256 + threadIdx.x;
    int n0 = blockIdx.y * 128;
    int z = blockIdx.z;
    const u16* p = P + (long long)z * 1048576;
    float s = 0.f;
    for (int n = n0; n < n0 + 128; n++) s += bf2f(p[(long long)n * 1024 + m]);
    atomicAdd(&colsumP[z * 1024 + m], s);
}

// ---------------- S[z][j] = sum_n gwn[z][n][j] ----------------
__global__ __launch_bounds__(256) void sgw_k(const u16* __restrict__ gwn, float* __restrict__ S) {
    int z = blockIdx.x;
    int j = threadIdx.x & 63, part = threadIdx.x >> 6;
    __shared__ float lds[4][64];
    float s = 0.f;
    for (int i = 0; i < 256; i++)
        s += bf2f(gwn[((long long)z * 1024 + part * 256 + i) * 64 + j]);
    lds[part][j] = s;
    __syncthreads();
    if (threadIdx.x < 64) S[z * 64 + threadIdx.x] =
        lds[0][threadIdx.x] + lds[1][threadIdx.x] + lds[2][threadIdx.x] + lds[3][threadIdx.x];
}

// ---------------- colsum[z][m] = (1-a)*colsumP + a * (gwn[m] . S) ----------------
__global__ __launch_bounds__(256) void combine_k(const float* __restrict__ colsumP,
                                                 const u16* __restrict__ gwn, const float* __restrict__ S,
                                                 const float* __restrict__ alpha, float* __restrict__ colsum) {
    int m = blockIdx.x * 256 + threadIdx.x;
    int z = blockIdx.y, h = z % 12;
    float a = sigm(alpha[h]);
    const u16* g = gwn + ((long long)z * 1024 + m) * 64;
    const float* Sz = S + z * 64;
    float dot = 0.f;
#pragma unroll 8
    for (int j = 0; j < 64; j++) dot += bf2f(g[j]) * Sz[j];
    colsum[z * 1024 + m] = (1.f - a) * colsumP[z * 1024 + m] + a * dot;
}

// ---------------- v'^T: vpt[z][d][m] = vh[z][m][d] / (colsum+1e-8), bf16 ----------------
__global__ __launch_bounds__(256) void vpt_k(const u16* __restrict__ vh, const float* __restrict__ colsum,
                                             u16* __restrict__ vpt) {
    int z = blockIdx.y, m0 = blockIdx.x * 64;
    __shared__ float ts[64 * 65];
    int mi = threadIdx.x >> 6, d = threadIdx.x & 63;
    for (int rr = 0; rr < 16; rr++) {
        int row = rr * 4 + mi;
        ts[row * 65 + d] = bf2f(vh[((long long)z * 1024 + m0 + row) * 64 + d]);
    }
    __syncthreads();
    int mj = threadIdx.x & 63, d0 = threadIdx.x >> 6;
    for (int rr = 0; rr < 16; rr++) {
        int dd = rr * 4 + d0;
        float cs = colsum[z * 1024 + m0 + mj] + 1e-8f;
        vpt[((long long)z * 64 + dd) * 1024 + m0 + mj] = f2bf(ts[mj * 65 + dd] / cs);
    }
}

// ---------------- Wt[z][d][j] = sum_n gwn[z][n][j] * v'[z][n][d]  (atomic accumulate) ----------------
__global__ __launch_bounds__(256) void wgemm_k(const u16* __restrict__ gwn, const u16* __restrict__ vpt,
                                               float* __restrict__ Wt) {
    int z = blockIdx.y, n0 = blockIdx.x * 128;
    __shared__ u16 gs[128 * 64];
    __shared__ u16 vs2[64 * 128];
    for (int i = threadIdx.x; i < 128 * 64; i += 256) {
        int nn = i >> 6, j = i & 63;
        gs[i] = gwn[((long long)z * 1024 + n0 + nn) * 64 + j];
        int d = i >> 7, n2 = i & 127;
        vs2[i] = vpt[((long long)z * 64 + d) * 1024 + n0 + n2];
    }
    for (int i = threadIdx.x + 32768 / 4; i < 128 * 64; i += 256) { }  // (no-op, keep simple)
    __syncthreads();
    int j = threadIdx.x & 63, dg = threadIdx.x >> 6;
    float acc[16] = {};
    for (int nn = 0; nn < 128; nn++) {
        float g = bf2f(gs[nn * 64 + j]);
#pragma unroll
        for (int i = 0; i < 16; i++) acc[i] += g * bf2f(vs2[(dg * 16 + i) * 128 + nn]);
    }
#pragma unroll
    for (int i = 0; i < 16; i++)
        atomicAdd(&Wt[((long long)z * 64 + dg * 16 + i) * 64 + j], acc[i]);
}

// ---------------- out = (1-a)*(P @ v') + a*(gwn @ W), head-merged bf16 [4096][768] ----------------
__global__ __launch_bounds__(256) void attn_out_k(const u16* __restrict__ P, const u16* __restrict__ vpt,
                                                  const u16* __restrict__ gwn, const float* __restrict__ Wt,
                                                  const float* __restrict__ alpha, u16* __restrict__ out) {
    __shared__ u16 As[128 * 32];
    __shared__ u16 Bs[64 * 32];
    const int tid = threadIdx.x, lane = tid & 63, wid = tid >> 6;
    const int l16 = lane & 15, qd = lane >> 4;
    const int bm0 = blockIdx.x * 128, z = blockIdx.y;
    const int h = z % 12, b = z / 12;
    const int wm0 = wid * 32;
    const u16* Pz = P + (long long)z * 1048576;
    const u16* vz = vpt + (long long)z * 65536;
    f32x4 accP[2][4] = {};
    f32x4 accG[2][4] = {};
    for (int k0 = 0; k0 < 1024; k0 += 32) {
        for (int c = tid; c < 512; c += 256) {
            int row = c >> 2, kc = (c & 3) * 8;
            *reinterpret_cast<u32x4*>(&As[row * 32 + kc]) =
                *reinterpret_cast<const u32x4*>(&Pz[(long long)(bm0 + row) * 1024 + k0 + kc]);
        }
        for (int c = tid; c < 256; c += 256) {
            int row = c >> 2, kc = (c & 3) * 8;
            *reinterpret_cast<u32x4*>(&Bs[row * 32 + kc]) =
                *reinterpret_cast<const u32x4*>(&vz[(long long)row * 1024 + k0 + kc]);
        }
        __syncthreads();
        bf16x8 af[2], bv[4];
#pragma unroll
        for (int i = 0; i < 2; i++) af[i] = ldfrag(&As[(wm0 + i * 16 + l16) * 32 + qd * 8]);
#pragma unroll
        for (int j = 0; j < 4; j++) bv[j] = ldfrag(&Bs[(j * 16 + l16) * 32 + qd * 8]);
#pragma unroll
        for (int i = 0; i < 2; i++)
#pragma unroll
            for (int j = 0; j < 4; j++)
                accP[i][j] = __builtin_amdgcn_mfma_f32_16x16x32_bf16(af[i], bv[j], accP[i][j], 0, 0, 0);
        __syncthreads();
    }
    const u16* gz = gwn + (long long)z * 65536;
    const float* wz = Wt + (long long)z * 4096;
    for (int k0 = 0; k0 < 64; k0 += 32) {
        for (int c = tid; c < 512; c += 256) {
            int row = c >> 2, kc = (c & 3) * 8;
            *reinterpret_cast<u32x4*>(&As[row * 32 + kc]) =
                *reinterpret_cast<const u32x4*>(&gz[(long long)(bm0 + row) * 64 + k0 + kc]);
        }
        for (int i = tid; i < 2048; i += 256) {
            int d = i >> 5, jc = i & 31;
            Bs[d * 32 + jc] = f2bf(wz[d * 64 + k0 + jc]);
        }
        __syncthreads();
        bf16x8 af[2], bv[4];
#pragma unroll
        for (int i = 0; i < 2; i++) af[i] = ldfrag(&As[(wm0 + i * 16 + l16) * 32 + qd * 8]);
#pragma unroll
        for (int j = 0; j < 4; j++) bv[j] = ldfrag(&Bs[(j * 16 + l16) * 32 + qd * 8]);
#pragma unroll
        for (int i = 0; i < 2; i++)
#pragma unroll
            for (int j = 0; j < 4; j++)
                accG[i][j] = __builtin_amdgcn_mfma_f32_16x16x32_bf16(af[i], bv[j], accG[i][j], 0, 0, 0);
        __syncthreads();
    }
    float a = sigm(alpha[h]);
#pragma unroll
    for (int i = 0; i < 2; i++)
#pragma unroll
        for (int j = 0; j < 4; j++)
#pragma unroll
            for (int r = 0; r < 4; r++) {
                int n = bm0 + wm0 + i * 16 + qd * 4 + r;
                int d = j * 16 + l16;
                float v = (1.f - a) * accP[i][j][r] + a * accG[i][j][r];
                out[((long long)(b * 1024 + n)) * 768 + h * 64 + d] = f2bf(v);
            }
}

// =======================================================================================
extern "C" void kernel_launch(void* const* d_in, const int* in_sizes, int n_in,
                              void* d_out, int out_size, void* d_ws, size_t ws_size,
                              hipStream_t stream) {
    const float* x      = (const float*)d_in[0];
    const float* ln1_w  = (const float*)d_in[1];
    const float* ln1_b  = (const float*)d_in[2];
    const float* qkv_w  = (const float*)d_in[3];
    const float* qkv_b  = (const float*)d_in[4];
    const float* proj_w = (const float*)d_in[5];
    const float* proj_b = (const float*)d_in[6];
    const float* gp_w   = (const float*)d_in[7];
    const float* alpha  = (const float*)d_in[8];
    const float* ln2_w  = (const float*)d_in[9];
    const float* ln2_b  = (const float*)d_in[10];
    const float* ff1_w  = (const float*)d_in[11];
    const float* ff1_b  = (const float*)d_in[12];
    const float* ff2_w  = (const float*)d_in[13];
    const float* ff2_b  = (const float*)d_in[14];

    char* w = (char*)d_ws;
    size_t off = 0;
    auto alloc = [&](size_t bytes) { size_t r = off; off += (bytes + 255) & ~(size_t)255; return r; };

    u16*   xn_bf   = (u16*)(w + alloc(4096LL * 768 * 2));
    u16*   wqkv_t  = (u16*)(w + alloc(2304LL * 768 * 2));
    u16*   wproj_t = (u16*)(w + alloc(768LL * 768 * 2));
    u16*   wff1_t  = (u16*)(w + alloc(3072LL * 768 * 2));
    u16*   wff2_t  = (u16*)(w + alloc(768LL * 3072 * 2));
    u16*   qkvB    = (u16*)(w + alloc(4096LL * 2304 * 2));   // later: attn_o + xn2
    u16*   qh      = (u16*)(w + alloc(48LL * 1024 * 64 * 2));
    u16*   kh      = (u16*)(w + alloc(48LL * 1024 * 64 * 2));
    u16*   vh      = (u16*)(w + alloc(48LL * 1024 * 64 * 2));
    u16*   gwn     = (u16*)(w + alloc(48LL * 1024 * 64 * 2));
    u16*   tbuf    = (u16*)(w + alloc(48LL * 1024 * 1024 * 2));  // t -> P; later proj_out + hmid
    float* colsumP = (float*)(w + alloc(48LL * 1024 * 4));
    float* Sbuf    = (float*)(w + alloc(48LL * 64 * 4));
    float* Wt      = (float*)(w + alloc(48LL * 64 * 64 * 4));
    float* colsum  = (float*)(w + alloc(48LL * 1024 * 4));
    u16*   vpt     = (u16*)(w + alloc(48LL * 64 * 1024 * 2));
    float* x1      = (float*)(w + alloc(4096LL * 768 * 4));
    // region reuse (dead buffers)
    u16*   attn_o   = qkvB;                               // qkvB dead after repack/gw0
    u16*   xn2      = qkvB + 4096LL * 768;
    float* proj_out = (float*)tbuf;                       // P dead after attn_out_k
    u16*   hmid     = (u16*)((char*)tbuf + 4096LL * 768 * 4);

    dim3 blk(256);

    // weight transpose-casts
    tcast_k<<<dim3(72, 24), dim3(32, 8), 0, stream>>>(qkv_w, wqkv_t, 768, 2304);
    tcast_k<<<dim3(24, 24), dim3(32, 8), 0, stream>>>(proj_w, wproj_t, 768, 768);
    tcast_k<<<dim3(96, 24), dim3(32, 8), 0, stream>>>(ff1_w, wff1_t, 768, 3072);
    tcast_k<<<dim3(24, 96), dim3(32, 8), 0, stream>>>(ff2_w, wff2_t, 3072, 768);

    // LN1
    ln_k<<<dim3(4096), blk, 0, stream>>>(x, nullptr, ln1_w, ln1_b, xn_bf, nullptr);

    // QKV GEMM -> bf16 qkvB
    {
        GemmP p = {xn_bf, wqkv_t, nullptr, qkvB, qkv_b, nullptr, 4096, 2304, 768, 768, 768, 2304, 1};
        gemm_bt<<<dim3(18, 32), blk, 0, stream>>>(p);
    }

    // repack q,k,v ; group weights
    repack_qkv_k<<<dim3(12288), blk, 0, stream>>>(qkvB, qh, kh, vh);
    gw0_k<<<dim3(16, 48), blk, 0, stream>>>(vh, gp_w, gwn);

    // t = (q@k^T) * (gwn@gwn^T)
    attn_tg_k<<<dim3(8, 8, 48), blk, 0, stream>>>(qh, kh, gwn, tbuf);

    // P = softmax rows (in place)
    rowsoft_k<<<dim3(1024, 48), blk, 0, stream>>>(tbuf);

    // column sums of P
    zero_k<<<dim3(192), blk, 0, stream>>>(colsumP);
    colsumP_k<<<dim3(4, 8, 48), blk, 0, stream>>>(tbuf, colsumP);

    // S, combined colsum, v'^T
    sgw_k<<<dim3(48), blk, 0, stream>>>(gwn, Sbuf);
    combine_k<<<dim3(4, 48), blk, 0, stream>>>(colsumP, gwn, Sbuf, alpha, colsum);
    vpt_k<<<dim3(16, 48), blk, 0, stream>>>(vh, colsum, vpt);

    // Wt = (gwn^T @ v')^T
    zero_k<<<dim3(768), blk, 0, stream>>>(Wt);
    wgemm_k<<<dim3(8, 48), blk, 0, stream>>>(gwn, vpt, Wt);

    // attention output (head-merged bf16)
    attn_out_k<<<dim3(8, 48), blk, 0, stream>>>(tbuf, vpt, gwn, Wt, alpha, attn_o);

    // proj GEMM -> proj_out fp32 (tbuf region; P is dead)
    {
        GemmP p = {attn_o, wproj_t, proj_out, nullptr, proj_b, nullptr, 4096, 768, 768, 768, 768, 768, 0};
        gemm_bt<<<dim3(6, 32), blk, 0, stream>>>(p);
    }

    // x1 = proj_out + x ; LN2 -> xn2
    ln_k<<<dim3(4096), blk, 0, stream>>>(proj_out, x, ln2_w, ln2_b, xn2, x1);

    // FF1 + gelu -> hmid bf16
    {
        GemmP p = {xn2, wff1_t, nullptr, hmid, ff1_b, nullptr, 4096, 3072, 768, 768, 768, 3072, 2};
        gemm_bt<<<dim3(24, 32), blk, 0, stream>>>(p);
    }

    // FF2 + residual -> d_out fp32
    {
        GemmP p = {hmid, wff2_t, (float*)d_out, nullptr, ff2_b, x1, 4096, 768, 3072, 3072, 3072, 768, 3};
        gemm_bt<<<dim3(6, 32), blk, 0, stream>>>(p);
    }
}

// Round 3
// 618.767 us; speedup vs baseline: 1.0653x; 1.0653x over previous
//
#include <hip/hip_runtime.h>
#include <hip/hip_bf16.h>
#include <math.h>

#define DEVI __device__ __forceinline__

typedef __bf16 bf16x8 __attribute__((ext_vector_type(8)));
typedef float f32x4 __attribute__((ext_vector_type(4)));
typedef unsigned int u32x4 __attribute__((ext_vector_type(4)));
typedef unsigned short u16;

DEVI u16 f2bf(float f) {
    __hip_bfloat16 h = __float2bfloat16(f);
    return __builtin_bit_cast(u16, h);
}
DEVI float bf2f(u16 u) {
    unsigned int x = ((unsigned int)u) << 16;
    return __builtin_bit_cast(float, x);
}
DEVI float gelu_f(float x) { return 0.5f * x * (1.f + erff(x * 0.70710678118654752f)); }
DEVI float sigm(float x) { return 1.f / (1.f + expf(-x)); }

DEVI bf16x8 ldfrag(const u16* p) {
    return __builtin_bit_cast(bf16x8, *reinterpret_cast<const u32x4*>(p));
}

// async global->LDS, 16B per lane, LDS dest = wave-uniform base + lane*16
DEVI void gload_lds16(const u16* g, u16* l) {
    __builtin_amdgcn_global_load_lds(
        (const __attribute__((address_space(1))) void*)g,
        (__attribute__((address_space(3))) void*)l, 16, 0, 0);
}
// stage 128 rows x 32 u16 (8KB): 2 chunks of 1024B per wave
DEVI void stage128(const u16* gbase, int stride, u16* lds, int wave, int lane) {
#pragma unroll
    for (int t = 0; t < 2; t++) {
        int c = wave * 2 + t;
        const u16* g = gbase + (long long)(c * 16 + (lane >> 2)) * stride + (lane & 3) * 8;
        gload_lds16(g, lds + c * 512);
    }
}
// stage 64 rows x 32 u16 (4KB): 1 chunk per wave
DEVI void stage64(const u16* gbase, int stride, u16* lds, int wave, int lane) {
    const u16* g = gbase + (long long)(wave * 16 + (lane >> 2)) * stride + (lane & 3) * 8;
    gload_lds16(g, lds + wave * 512);
}

// ---------------- zero fill ----------------
__global__ __launch_bounds__(256) void zero_k(float* __restrict__ p) {
    p[(long long)blockIdx.x * 256 + threadIdx.x] = 0.f;
}

// ---------------- transpose + cast fp32 -> bf16 ----------------
__global__ __launch_bounds__(256) void tcast_k(const float* __restrict__ in, u16* __restrict__ out,
                                               int R, int C) {
    __shared__ float tile[32][33];
    int c0 = blockIdx.x * 32, r0 = blockIdx.y * 32;
    for (int ry = threadIdx.y; ry < 32; ry += 8)
        tile[ry][threadIdx.x] = in[(long long)(r0 + ry) * C + c0 + threadIdx.x];
    __syncthreads();
    for (int cy = threadIdx.y; cy < 32; cy += 8)
        out[(long long)(c0 + cy) * R + r0 + threadIdx.x] = f2bf(tile[threadIdx.x][cy]);
}

// ---------------- layernorm over 768 ----------------
__global__ __launch_bounds__(256) void ln_k(const float* __restrict__ in1, const float* __restrict__ in2,
                                            const float* __restrict__ w, const float* __restrict__ b,
                                            u16* __restrict__ outbf, float* __restrict__ x1out) {
    int row = blockIdx.x;
    long long ro = (long long)row * 768;
    __shared__ float lds1[4], lds2[4];
    float v[3];
    float s = 0.f, sq = 0.f;
#pragma unroll
    for (int j = 0; j < 3; j++) {
        int c = threadIdx.x + j * 256;
        float x = in1[ro + c];
        if (in2) x += in2[ro + c];
        v[j] = x; s += x; sq += x * x;
    }
    if (x1out) {
#pragma unroll
        for (int j = 0; j < 3; j++) x1out[ro + threadIdx.x + j * 256] = v[j];
    }
    for (int off = 32; off; off >>= 1) { s += __shfl_down(s, off); sq += __shfl_down(sq, off); }
    int wid = threadIdx.x >> 6;
    if ((threadIdx.x & 63) == 0) { lds1[wid] = s; lds2[wid] = sq; }
    __syncthreads();
    s = lds1[0] + lds1[1] + lds1[2] + lds1[3];
    sq = lds2[0] + lds2[1] + lds2[2] + lds2[3];
    float mu = s * (1.f / 768.f);
    float var = sq * (1.f / 768.f) - mu * mu;
    float rs = rsqrtf(var + 1e-5f);
#pragma unroll
    for (int j = 0; j < 3; j++) {
        int c = threadIdx.x + j * 256;
        outbf[ro + c] = f2bf((v[j] - mu) * rs * w[c] + b[c]);
    }
}

// ---------------- generic MFMA GEMM: C = A @ B_t^T, optional split-K ----------------
struct GemmP {
    const u16* A; const u16* B;
    float* outF; u16* outB;
    const float* bias; const float* res;
    int M, N, K, lda, ldb, ldc;
    int epi;     // 0:f32+bias 1:bf16+bias 2:bf16+bias+gelu 3:f32+bias+res
    int splits;  // if >1: atomicAdd fp32 out (pre-zeroed); split 0 adds bias(+res)
};

__global__ __launch_bounds__(256) void gemm_bt(GemmP p) {
    __shared__ u16 As[128 * 32];
    __shared__ u16 Bs[128 * 32];
    const int tid = threadIdx.x, lane = tid & 63, wave = tid >> 6;
    const int l16 = lane & 15, qd = lane >> 4;
    const int bm0 = blockIdx.y * 128, bn0 = blockIdx.x * 128;
    const int wm0 = (wave >> 1) * 64, wn0 = (wave & 1) * 64;
    const int kc = p.K / p.splits;
    const int kbeg = blockIdx.z * kc, kend = kbeg + kc;
    f32x4 acc[4][4] = {};
    for (int k0 = kbeg; k0 < kend; k0 += 32) {
        stage128(p.A + (long long)bm0 * p.lda + k0, p.lda, As, wave, lane);
        stage128(p.B + (long long)bn0 * p.ldb + k0, p.ldb, Bs, wave, lane);
        __syncthreads();
        bf16x8 af[4], bv[4];
#pragma unroll
        for (int i = 0; i < 4; i++) af[i] = ldfrag(&As[(wm0 + i * 16 + l16) * 32 + qd * 8]);
#pragma unroll
        for (int j = 0; j < 4; j++) bv[j] = ldfrag(&Bs[(wn0 + j * 16 + l16) * 32 + qd * 8]);
#pragma unroll
        for (int i = 0; i < 4; i++)
#pragma unroll
            for (int j = 0; j < 4; j++)
                acc[i][j] = __builtin_amdgcn_mfma_f32_16x16x32_bf16(af[i], bv[j], acc[i][j], 0, 0, 0);
        __syncthreads();
    }
#pragma unroll
    for (int i = 0; i < 4; i++)
#pragma unroll
        for (int j = 0; j < 4; j++)
#pragma unroll
            for (int r = 0; r < 4; r++) {
                int row = bm0 + wm0 + i * 16 + qd * 4 + r;
                int col = bn0 + wn0 + j * 16 + l16;
                float v = acc[i][j][r];
                long long o = (long long)row * p.ldc + col;
                if (p.splits == 1) {
                    switch (p.epi) {
                        case 0: p.outF[o] = v + p.bias[col]; break;
                        case 1: p.outB[o] = f2bf(v + p.bias[col]); break;
                        case 2: p.outB[o] = f2bf(gelu_f(v + p.bias[col])); break;
                        default: p.outF[o] = v + p.bias[col] + p.res[o]; break;
                    }
                } else {
                    if (blockIdx.z == 0) {
                        v += p.bias[col];
                        if (p.epi == 3) v += p.res[o];
                    }
                    atomicAdd(&p.outF[o], v);
                }
            }
}

// ---------------- repack qkv (bf16 [4096][2304]) into per-head q,k,v [48][1024][64] ----------------
__global__ __launch_bounds__(256) void repack_qkv_k(const u16* __restrict__ qkvB,
                                                    u16* __restrict__ qh, u16* __restrict__ kh,
                                                    u16* __restrict__ vh) {
    long long idx = (long long)blockIdx.x * 256 + threadIdx.x;
    int r = (int)(idx / 768), c = (int)(idx % 768);
    int b = r >> 10, n = r & 1023, h = c >> 6, d = c & 63;
    long long src = (long long)r * 2304;
    long long o = ((long long)(b * 12 + h) * 1024 + n) * 64 + d;
    qh[o] = f2bf(bf2f(qkvB[src + c]) * 0.125f);
    kh[o] = qkvB[src + 768 + c];
    vh[o] = qkvB[src + 1536 + c];
}

// ---------------- gwn = softmax(gelu(v @ gp^T)) per head, padded to 64 cols, bf16 ----------------
__global__ __launch_bounds__(256) void gw0_k(const u16* __restrict__ vh, const float* __restrict__ gp_w,
                                             u16* __restrict__ gwn) {
    int z = blockIdx.y, n0 = blockIdx.x * 64;
    int h = z % 12;
    __shared__ float gps[49 * 64];
    __shared__ float vs[64 * 64];
    __shared__ float gws[64 * 52];
    for (int i = threadIdx.x; i < 49 * 64; i += 256) gps[i] = gp_w[h * 3136 + i];
    for (int i = threadIdx.x; i < 64 * 64; i += 256) {
        int n = i >> 6, d = i & 63;
        vs[i] = bf2f(vh[((long long)z * 1024 + n0 + n) * 64 + d]);
    }
    __syncthreads();
    for (int o = threadIdx.x; o < 64 * 49; o += 256) {
        int n = o / 49, m = o % 49;
        float s = 0.f;
#pragma unroll 8
        for (int kk = 0; kk < 64; kk++) s += vs[n * 64 + kk] * gps[m * 64 + kk];
        gws[n * 52 + m] = gelu_f(s);
    }
    __syncthreads();
    if (threadIdx.x < 64) {
        int n = threadIdx.x;
        float mx = -1e30f;
        for (int m = 0; m < 49; m++) mx = fmaxf(mx, gws[n * 52 + m]);
        float se = 0.f;
        for (int m = 0; m < 49; m++) se += expf(gws[n * 52 + m] - mx);
        float inv = 1.f / se;
        long long o = ((long long)z * 1024 + n0 + n) * 64;
        for (int m = 0; m < 49; m++) gwn[o + m] = f2bf(expf(gws[n * 52 + m] - mx) * inv);
        for (int m = 49; m < 64; m++) gwn[o + m] = 0;
    }
}

// ---------------- e = exp((q@k^T)*(gwn@gwn^T)), bf16; rowsumE += exact fp32 row sums ----------------
__global__ __launch_bounds__(256) void attn_tg_k(const u16* __restrict__ qh, const u16* __restrict__ kh,
                                                 const u16* __restrict__ gwn, u16* __restrict__ e,
                                                 float* __restrict__ rowsumE) {
    __shared__ u16 As[128 * 32];
    __shared__ u16 Bs[128 * 32];
    const int tid = threadIdx.x, lane = tid & 63, wave = tid >> 6;
    const int l16 = lane & 15, qd = lane >> 4;
    const int bm0 = blockIdx.y * 128, bn0 = blockIdx.x * 128, z = blockIdx.z;
    const int wm0 = (wave >> 1) * 64, wn0 = (wave & 1) * 64;
    const u16* qz = qh + (long long)z * 65536;
    const u16* kz = kh + (long long)z * 65536;
    const u16* gz = gwn + (long long)z * 65536;
    f32x4 accS[4][4] = {};
    f32x4 accG[4][4] = {};
    for (int ph = 0; ph < 2; ph++) {
        const u16* pa = ph ? gz : qz;
        const u16* pb = ph ? gz : kz;
        for (int k0 = 0; k0 < 64; k0 += 32) {
            stage128(pa + (long long)bm0 * 64 + k0, 64, As, wave, lane);
            stage128(pb + (long long)bn0 * 64 + k0, 64, Bs, wave, lane);
            __syncthreads();
            bf16x8 af[4], bv[4];
#pragma unroll
            for (int i = 0; i < 4; i++) af[i] = ldfrag(&As[(wm0 + i * 16 + l16) * 32 + qd * 8]);
#pragma unroll
            for (int j = 0; j < 4; j++) bv[j] = ldfrag(&Bs[(wn0 + j * 16 + l16) * 32 + qd * 8]);
            if (ph == 0) {
#pragma unroll
                for (int i = 0; i < 4; i++)
#pragma unroll
                    for (int j = 0; j < 4; j++)
                        accS[i][j] = __builtin_amdgcn_mfma_f32_16x16x32_bf16(af[i], bv[j], accS[i][j], 0, 0, 0);
            } else {
#pragma unroll
                for (int i = 0; i < 4; i++)
#pragma unroll
                    for (int j = 0; j < 4; j++)
                        accG[i][j] = __builtin_amdgcn_mfma_f32_16x16x32_bf16(af[i], bv[j], accG[i][j], 0, 0, 0);
            }
            __syncthreads();
        }
    }
    long long zoff = (long long)z * 1048576;
#pragma unroll
    for (int i = 0; i < 4; i++)
#pragma unroll
        for (int r = 0; r < 4; r++) {
            int row = bm0 + wm0 + i * 16 + qd * 4 + r;
            float rs = 0.f;
#pragma unroll
            for (int j = 0; j < 4; j++) {
                int col = bn0 + wn0 + j * 16 + l16;
                float ev = expf(accS[i][j][r] * accG[i][j][r]);  // |t| <~ 2, no max-sub needed
                e[zoff + (long long)row * 1024 + col] = f2bf(ev);
                rs += ev;
            }
            rs += __shfl_xor(rs, 1); rs += __shfl_xor(rs, 2);
            rs += __shfl_xor(rs, 4); rs += __shfl_xor(rs, 8);
            if (l16 == 0) atomicAdd(&rowsumE[z * 1024 + row], rs);
        }
}

// ---------------- S[z][j] = sum_n gwn[z][n][j] ----------------
__global__ __launch_bounds__(256) void sgw_k(const u16* __restrict__ gwn, float* __restrict__ S) {
    int z = blockIdx.x;
    int j = threadIdx.x & 63, part = threadIdx.x >> 6;
    __shared__ float lds[4][64];
    float s = 0.f;
    for (int i = 0; i < 256; i++)
        s += bf2f(gwn[((long long)z * 1024 + part * 256 + i) * 64 + j]);
    lds[part][j] = s;
    __syncthreads();
    if (threadIdx.x < 64) S[z * 64 + threadIdx.x] =
        lds[0][threadIdx.x] + lds[1][threadIdx.x] + lds[2][threadIdx.x] + lds[3][threadIdx.x];
}

// ---------------- colsum init: colsum[z][m] = a * (gwn[m] . S) ----------------
__global__ __launch_bounds__(256) void combine_k(const u16* __restrict__ gwn, const float* __restrict__ S,
                                                 const float* __restrict__ alpha, float* __restrict__ colsum) {
    int m = blockIdx.x * 256 + threadIdx.x;
    int z = blockIdx.y, h = z % 12;
    float a = sigm(alpha[h]);
    const u16* g = gwn + ((long long)z * 1024 + m) * 64;
    const float* Sz = S + z * 64;
    float dot = 0.f;
#pragma unroll 8
    for (int j = 0; j < 64; j++) dot += bf2f(g[j]) * Sz[j];
    colsum[z * 1024 + m] = a * dot;
}

// ---------------- colsum[z][m] += (1-a) * sum_n e[n][m]/rowsum[n] ----------------
__global__ __launch_bounds__(256) void colsumE_k(const u16* __restrict__ e, const float* __restrict__ rowsumE,
                                                 const float* __restrict__ alpha, float* __restrict__ colsum) {
    int m = blockIdx.x * 256 + threadIdx.x;
    int n0 = blockIdx.y * 128;
    int z = blockIdx.z, h = z % 12;
    float a = sigm(alpha[h]);
    const u16* p = e + (long long)z * 1048576;
    const float* rs = rowsumE + z * 1024;
    float s = 0.f;
    for (int n = n0; n < n0 + 128; n++) s += bf2f(p[(long long)n * 1024 + m]) * (1.f / rs[n]);
    atomicAdd(&colsum[z * 1024 + m], (1.f - a) * s);
}

// ---------------- v'^T: vpt[z][d][m] = vh[z][m][d] / (colsum+1e-8), bf16 ----------------
__global__ __launch_bounds__(256) void vpt_k(const u16* __restrict__ vh, const float* __restrict__ colsum,
                                             u16* __restrict__ vpt) {
    int z = blockIdx.y, m0 = blockIdx.x * 64;
    __shared__ float ts[64 * 65];
    int mi = threadIdx.x >> 6, d = threadIdx.x & 63;
    for (int rr = 0; rr < 16; rr++) {
        int row = rr * 4 + mi;
        ts[row * 65 + d] = bf2f(vh[((long long)z * 1024 + m0 + row) * 64 + d]);
    }
    __syncthreads();
    int mj = threadIdx.x & 63, d0 = threadIdx.x >> 6;
    for (int rr = 0; rr < 16; rr++) {
        int dd = rr * 4 + d0;
        float cs = colsum[z * 1024 + m0 + mj] + 1e-8f;
        vpt[((long long)z * 64 + dd) * 1024 + m0 + mj] = f2bf(ts[mj * 65 + dd] / cs);
    }
}

// ---------------- Wt[z][d][j] = sum_n gwn[z][n][j] * v'[z][n][d] ----------------
__global__ __launch_bounds__(256) void wgemm_k(const u16* __restrict__ gwn, const u16* __restrict__ vpt,
                                               float* __restrict__ Wt) {
    int z = blockIdx.y, n0 = blockIdx.x * 128;
    __shared__ u16 gs[128 * 64];
    __shared__ u16 vs2[64 * 128];
    for (int i = threadIdx.x; i < 128 * 64; i += 256) {
        int nn = i >> 6, j = i & 63;
        gs[i] = gwn[((long long)z * 1024 + n0 + nn) * 64 + j];
        int d = i >> 7, n2 = i & 127;
        vs2[i] = vpt[((long long)z * 64 + d) * 1024 + n0 + n2];
    }
    __syncthreads();
    int j = threadIdx.x & 63, dg = threadIdx.x >> 6;
    float acc[16] = {};
    for (int nn = 0; nn < 128; nn++) {
        float g = bf2f(gs[nn * 64 + j]);
#pragma unroll
        for (int i = 0; i < 16; i++) acc[i] += g * bf2f(vs2[(dg * 16 + i) * 128 + nn]);
    }
#pragma unroll
    for (int i = 0; i < 16; i++)
        atomicAdd(&Wt[((long long)z * 64 + dg * 16 + i) * 64 + j], acc[i]);
}

// ---------------- out = (1-a)/rowsum * (e @ v') + a*(gwn @ W), head-merged bf16 ----------------
__global__ __launch_bounds__(256) void attn_out_k(const u16* __restrict__ e, const u16* __restrict__ vpt,
                                                  const u16* __restrict__ gwn, const float* __restrict__ Wt,
                                                  const float* __restrict__ rowsumE,
                                                  const float* __restrict__ alpha, u16* __restrict__ out) {
    __shared__ u16 As[128 * 32];
    __shared__ u16 Bs[64 * 32];
    const int tid = threadIdx.x, lane = tid & 63, wave = tid >> 6;
    const int l16 = lane & 15, qd = lane >> 4;
    const int bm0 = blockIdx.x * 128, z = blockIdx.y;
    const int h = z % 12, b = z / 12;
    const int wm0 = wave * 32;
    const u16* Pz = e + (long long)z * 1048576;
    const u16* vz = vpt + (long long)z * 65536;
    f32x4 accP[2][4] = {};
    f32x4 accG[2][4] = {};
    for (int k0 = 0; k0 < 1024; k0 += 32) {
        stage128(Pz + (long long)bm0 * 1024 + k0, 1024, As, wave, lane);
        stage64(vz + k0, 1024, Bs, wave, lane);
        __syncthreads();
        bf16x8 af[2], bv[4];
#pragma unroll
        for (int i = 0; i < 2; i++) af[i] = ldfrag(&As[(wm0 + i * 16 + l16) * 32 + qd * 8]);
#pragma unroll
        for (int j = 0; j < 4; j++) bv[j] = ldfrag(&Bs[(j * 16 + l16) * 32 + qd * 8]);
#pragma unroll
        for (int i = 0; i < 2; i++)
#pragma unroll
            for (int j = 0; j < 4; j++)
                accP[i][j] = __builtin_amdgcn_mfma_f32_16x16x32_bf16(af[i], bv[j], accP[i][j], 0, 0, 0);
        __syncthreads();
    }
    const u16* gz = gwn + (long long)z * 65536;
    const float* wz = Wt + (long long)z * 4096;
    for (int k0 = 0; k0 < 64; k0 += 32) {
        stage128(gz + (long long)bm0 * 64 + k0, 64, As, wave, lane);
        for (int i = tid; i < 2048; i += 256) {
            int d = i >> 5, jc = i & 31;
            Bs[d * 32 + jc] = f2bf(wz[d * 64 + k0 + jc]);
        }
        __syncthreads();
        bf16x8 af[2], bv[4];
#pragma unroll
        for (int i = 0; i < 2; i++) af[i] = ldfrag(&As[(wm0 + i * 16 + l16) * 32 + qd * 8]);
#pragma unroll
        for (int j = 0; j < 4; j++) bv[j] = ldfrag(&Bs[(j * 16 + l16) * 32 + qd * 8]);
#pragma unroll
        for (int i = 0; i < 2; i++)
#pragma unroll
            for (int j = 0; j < 4; j++)
                accG[i][j] = __builtin_amdgcn_mfma_f32_16x16x32_bf16(af[i], bv[j], accG[i][j], 0, 0, 0);
        __syncthreads();
    }
    float a = sigm(alpha[h]);
#pragma unroll
    for (int i = 0; i < 2; i++)
#pragma unroll
        for (int r = 0; r < 4; r++) {
            int n = bm0 + wm0 + i * 16 + qd * 4 + r;
            float sc = (1.f - a) / rowsumE[z * 1024 + n];
#pragma unroll
            for (int j = 0; j < 4; j++) {
                int d = j * 16 + l16;
                float v = sc * accP[i][j][r] + a * accG[i][j][r];
                out[((long long)(b * 1024 + n)) * 768 + h * 64 + d] = f2bf(v);
            }
        }
}

// =======================================================================================
extern "C" void kernel_launch(void* const* d_in, const int* in_sizes, int n_in,
                              void* d_out, int out_size, void* d_ws, size_t ws_size,
                              hipStream_t stream) {
    const float* x      = (const float*)d_in[0];
    const float* ln1_w  = (const float*)d_in[1];
    const float* ln1_b  = (const float*)d_in[2];
    const float* qkv_w  = (const float*)d_in[3];
    const float* qkv_b  = (const float*)d_in[4];
    const float* proj_w = (const float*)d_in[5];
    const float* proj_b = (const float*)d_in[6];
    const float* gp_w   = (const float*)d_in[7];
    const float* alpha  = (const float*)d_in[8];
    const float* ln2_w  = (const float*)d_in[9];
    const float* ln2_b  = (const float*)d_in[10];
    const float* ff1_w  = (const float*)d_in[11];
    const float* ff1_b  = (const float*)d_in[12];
    const float* ff2_w  = (const float*)d_in[13];
    const float* ff2_b  = (const float*)d_in[14];

    char* w = (char*)d_ws;
    size_t off = 0;
    auto alloc = [&](size_t bytes) { size_t r = off; off += (bytes + 255) & ~(size_t)255; return r; };

    u16*   xn_bf   = (u16*)(w + alloc(4096LL * 768 * 2));
    u16*   wqkv_t  = (u16*)(w + alloc(2304LL * 768 * 2));
    u16*   wproj_t = (u16*)(w + alloc(768LL * 768 * 2));
    u16*   wff1_t  = (u16*)(w + alloc(3072LL * 768 * 2));
    u16*   wff2_t  = (u16*)(w + alloc(768LL * 3072 * 2));
    u16*   qkvB    = (u16*)(w + alloc(4096LL * 2304 * 2));   // later: attn_o + xn2
    u16*   qh      = (u16*)(w + alloc(48LL * 1024 * 64 * 2));
    u16*   kh      = (u16*)(w + alloc(48LL * 1024 * 64 * 2));
    u16*   vh      = (u16*)(w + alloc(48LL * 1024 * 64 * 2));
    u16*   gwn     = (u16*)(w + alloc(48LL * 1024 * 64 * 2));
    u16*   ebuf    = (u16*)(w + alloc(48LL * 1024 * 1024 * 2));  // exp(t); later proj_out + hmid
    float* rowsumE = (float*)(w + alloc(48LL * 1024 * 4));
    float* Sbuf    = (float*)(w + alloc(48LL * 64 * 4));
    float* Wt      = (float*)(w + alloc(48LL * 64 * 64 * 4));
    float* colsum  = (float*)(w + alloc(48LL * 1024 * 4));
    u16*   vpt     = (u16*)(w + alloc(48LL * 64 * 1024 * 2));
    float* x1      = (float*)(w + alloc(4096LL * 768 * 4));
    // region reuse (dead buffers)
    u16*   attn_o   = qkvB;                               // qkvB dead after repack/gw0
    u16*   xn2      = qkvB + 4096LL * 768;
    float* proj_out = (float*)ebuf;                       // e dead after attn_out_k
    u16*   hmid     = (u16*)((char*)ebuf + 4096LL * 768 * 4);

    dim3 blk(256);

    // weight transpose-casts
    tcast_k<<<dim3(72, 24), dim3(32, 8), 0, stream>>>(qkv_w, wqkv_t, 768, 2304);
    tcast_k<<<dim3(24, 24), dim3(32, 8), 0, stream>>>(proj_w, wproj_t, 768, 768);
    tcast_k<<<dim3(96, 24), dim3(32, 8), 0, stream>>>(ff1_w, wff1_t, 768, 3072);
    tcast_k<<<dim3(24, 96), dim3(32, 8), 0, stream>>>(ff2_w, wff2_t, 3072, 768);

    // LN1
    ln_k<<<dim3(4096), blk, 0, stream>>>(x, nullptr, ln1_w, ln1_b, xn_bf, nullptr);

    // QKV GEMM -> bf16 qkvB
    {
        GemmP p = {xn_bf, wqkv_t, nullptr, qkvB, qkv_b, nullptr, 4096, 2304, 768, 768, 768, 2304, 1, 1};
        gemm_bt<<<dim3(18, 32, 1), blk, 0, stream>>>(p);
    }

    // repack q,k,v ; group weights
    repack_qkv_k<<<dim3(12288), blk, 0, stream>>>(qkvB, qh, kh, vh);
    gw0_k<<<dim3(16, 48), blk, 0, stream>>>(vh, gp_w, gwn);

    // e = exp((q@k^T)*(gwn@gwn^T)) + exact rowsums
    zero_k<<<dim3(192), blk, 0, stream>>>(rowsumE);
    attn_tg_k<<<dim3(8, 8, 48), blk, 0, stream>>>(qh, kh, gwn, ebuf, rowsumE);

    // colsum = a*(gwn.S) + (1-a)*sum_n e/rowsum
    sgw_k<<<dim3(48), blk, 0, stream>>>(gwn, Sbuf);
    combine_k<<<dim3(4, 48), blk, 0, stream>>>(gwn, Sbuf, alpha, colsum);
    colsumE_k<<<dim3(4, 8, 48), blk, 0, stream>>>(ebuf, rowsumE, alpha, colsum);

    // v'^T
    vpt_k<<<dim3(16, 48), blk, 0, stream>>>(vh, colsum, vpt);

    // Wt = (gwn^T @ v')^T
    zero_k<<<dim3(768), blk, 0, stream>>>(Wt);
    wgemm_k<<<dim3(8, 48), blk, 0, stream>>>(gwn, vpt, Wt);

    // attention output (head-merged bf16)
    attn_out_k<<<dim3(8, 48), blk, 0, stream>>>(ebuf, vpt, gwn, Wt, rowsumE, alpha, attn_o);

    // proj GEMM -> proj_out fp32 (split-K x2, atomic; e dead)
    zero_k<<<dim3(12288), blk, 0, stream>>>(proj_out);
    {
        GemmP p = {attn_o, wproj_t, proj_out, nullptr, proj_b, nullptr, 4096, 768, 768, 768, 768, 768, 0, 2};
        gemm_bt<<<dim3(6, 32, 2), blk, 0, stream>>>(p);
    }

    // x1 = proj_out + x ; LN2 -> xn2
    ln_k<<<dim3(4096), blk, 0, stream>>>(proj_out, x, ln2_w, ln2_b, xn2, x1);

    // FF1 + gelu -> hmid bf16
    {
        GemmP p = {xn2, wff1_t, nullptr, hmid, ff1_b, nullptr, 4096, 3072, 768, 768, 768, 3072, 2, 1};
        gemm_bt<<<dim3(24, 32, 1), blk, 0, stream>>>(p);
    }

    // FF2 + residual -> d_out fp32 (split-K x4, atomic)
    zero_k<<<dim3(12288), blk, 0, stream>>>((float*)d_out);
    {
        GemmP p = {hmid, wff2_t, (float*)d_out, nullptr, ff2_b, x1, 4096, 768, 3072, 3072, 3072, 768, 3, 4};
        gemm_bt<<<dim3(6, 32, 4), blk, 0, stream>>>(p);
    }
}